// Round 1
// baseline (316.407 us; speedup 1.0000x reference)
//
#include <hip/hip_runtime.h>
#include <hip/hip_bf16.h>
#include <stdint.h>

#define TLEN 480
#define NB 128
#define NC 256

typedef short bf16x8 __attribute__((ext_vector_type(8)));
typedef float f32x4 __attribute__((ext_vector_type(4)));

__device__ inline unsigned short f2bf(float f) {
    union { float f; uint32_t u; } v; v.f = f;
    uint32_t u = v.u;
    return (unsigned short)((u + 0x7fffu + ((u >> 16) & 1u)) >> 16);
}

// degree-1 LOESS row (statsmodels-compatible), q <= n assumed (true for 7/17/29 vs 32/480)
__device__ void loess_row(int t, int n, int q, float* row) {
    int qq = q < n ? q : n;
    int left = t - (q - 1) / 2;
    if (left < 0) left = 0;
    if (left > n - qq) left = n - qq;
    int right = left + qq - 1;
    int h = (t - left) > (right - t) ? (t - left) : (right - t);
    double w[29];
    double wsum = 0.0;
    for (int i = 0; i < qq; ++i) {
        double dist = fabs((double)(left + i - t)) / (double)h;
        double u = 1.0 - dist * dist * dist;
        if (u < 0.0) u = 0.0;
        double wv = u * u * u;
        w[i] = wv; wsum += wv;
    }
    for (int i = 0; i < qq; ++i) w[i] /= wsum;
    double xbar = 0.0;
    for (int i = 0; i < qq; ++i) xbar += w[i] * (double)(left + i);
    double var = 0.0;
    for (int i = 0; i < qq; ++i) { double d = (double)(left + i) - xbar; var += w[i] * d * d; }
    if (var > 1e-12) {
        double tb = (double)t - xbar;
        for (int i = 0; i < qq; ++i) {
            double d = (double)(left + i) - xbar;
            row[left + i] = (float)(w[i] * (1.0 + tb * d / var));
        }
    } else {
        for (int i = 0; i < qq; ++i) row[left + i] = (float)w[i];
    }
}

__global__ void k_zero(float* p, int n) {
    int id = blockIdx.x * 256 + threadIdx.x;
    if (id < n) p[id] = 0.0f;
}

// builds M_seas (34x32), M_lp (480x480 windows), M_trend (480x480 windows), w3 (31-tap MA15*MA15*MA3)
__global__ void k_loess(float* Ms, float* w3, float* Mlp, float* Mt) {
    int i = threadIdx.x;
    if (i < 34) {
        loess_row(i - 1, 32, 7, Ms + i * 32);
    } else if (i < 34 + 480) {
        int t = i - 34;
        loess_row(t, TLEN, 17, Mlp + (size_t)t * TLEN);
    } else if (i < 34 + 960) {
        int t = i - 514;
        loess_row(t, TLEN, 29, Mt + (size_t)t * TLEN);
    } else if (i == 1000) {
        for (int d = 0; d <= 30; ++d) {
            int cnt = 0;
            for (int c = 0; c < 3; ++c)
                for (int a = 0; a < 15; ++a) {
                    int b = d - a - c;
                    if (b >= 0 && b < 15) cnt++;
                }
            w3[d] = (float)((double)cnt / 675.0);
        }
    }
}

// G[i][u] = sum_s M_seas[s][u/15] * w3[s*15 + u%15 - i]   (lp operator applied to subseries-extend op)
__global__ void k_G(const float* __restrict__ Ms, const float* __restrict__ w3, float* __restrict__ G) {
    int id = blockIdx.x * 256 + threadIdx.x;
    if (id >= TLEN * TLEN) return;
    int i = id / TLEN, u = id - i * TLEN;
    int ju = u % 15, nu = u / 15;
    float acc = 0.0f;
    for (int s = 0; s < 34; ++s) {
        int d = s * 15 + ju - i;
        if (d >= 0 && d <= 30) acc += Ms[s * 32 + nu] * w3[d];
    }
    G[id] = acc;
}

// S[t][u] = Ecenter[t][u] - sum_tau Mlp[t][tau]*G[tau][u]
__global__ void k_S(const float* __restrict__ Ms, const float* __restrict__ Mlp,
                    const float* __restrict__ G, float* __restrict__ S) {
    int id = blockIdx.x * 256 + threadIdx.x;
    if (id >= TLEN * TLEN) return;
    int t = id / TLEN, u = id - t * TLEN;
    int lo = t - 8;
    if (lo < 0) lo = 0;
    if (lo > TLEN - 17) lo = TLEN - 17;
    float acc = 0.0f;
    for (int k = 0; k < 17; ++k)
        acc += Mlp[(size_t)t * TLEN + lo + k] * G[(size_t)(lo + k) * TLEN + u];
    float val = -acc;
    if (t % 15 == u % 15) val += Ms[(1 + t / 15) * 32 + (u / 15)];
    S[id] = val;
}

// V = Mt @ S (banded 29), U = Mt - V
__global__ void k_VU(const float* __restrict__ Mt, const float* __restrict__ S,
                     float* __restrict__ U, float* __restrict__ V) {
    int id = blockIdx.x * 256 + threadIdx.x;
    if (id >= TLEN * TLEN) return;
    int t = id / TLEN, u = id - t * TLEN;
    int lo = t - 14;
    if (lo < 0) lo = 0;
    if (lo > TLEN - 29) lo = TLEN - 29;
    float acc = 0.0f;
    for (int k = 0; k < 29; ++k)
        acc += Mt[(size_t)t * TLEN + lo + k] * S[(size_t)(lo + k) * TLEN + u];
    V[id] = acc;
    U[id] = Mt[id] - acc;
}

// A = U + V@U, output bf16; classic 16x16 LDS-tiled fp32 matmul (480^3, tiny)
__global__ void k_A(const float* __restrict__ U, const float* __restrict__ V,
                    unsigned short* __restrict__ Abf) {
    __shared__ float Vs[16][17];
    __shared__ float Us[16][17];
    int tx = threadIdx.x, ty = threadIdx.y;
    int u = blockIdx.x * 16 + tx;
    int t = blockIdx.y * 16 + ty;
    float acc = 0.0f;
    for (int kt = 0; kt < 30; ++kt) {
        Vs[ty][tx] = V[(size_t)t * TLEN + kt * 16 + tx];
        Us[ty][tx] = U[(size_t)(kt * 16 + ty) * TLEN + u];
        __syncthreads();
        #pragma unroll
        for (int e = 0; e < 16; ++e) acc += Vs[ty][e] * Us[e][tx];
        __syncthreads();
    }
    Abf[(size_t)t * TLEN + u] = f2bf(U[(size_t)t * TLEN + u] + acc);
}

// x [128][480][256] fp32 -> Xt [128][256][480] bf16 (tile transpose via LDS)
__global__ void k_tr(const float* __restrict__ x, unsigned short* __restrict__ Xt) {
    __shared__ unsigned short Tt[32 * 36];
    int b = blockIdx.z, s0 = blockIdx.y * 32, c0 = blockIdx.x * 32;
    int i = threadIdx.x;
    int r = i >> 3, cg = i & 7;
    float4 v = *(const float4*)(x + (((size_t)b * TLEN + s0 + r) * NC + c0 + cg * 4));
    Tt[(cg * 4 + 0) * 36 + r] = f2bf(v.x);
    Tt[(cg * 4 + 1) * 36 + r] = f2bf(v.y);
    Tt[(cg * 4 + 2) * 36 + r] = f2bf(v.z);
    Tt[(cg * 4 + 3) * 36 + r] = f2bf(v.w);
    __syncthreads();
    int cl = i >> 3, ch = i & 7;
    ushort4 o = *(const ushort4*)&Tt[cl * 36 + ch * 4];
    *(ushort4*)(Xt + (((size_t)b * NC + c0 + cl) * TLEN + s0 + ch * 4)) = o;
}

// trend = A @ X_b per batch; out1 = trend, out0 = x - trend.
// Block: 48 rows (t) x 256 cols (c) of one batch. 4 waves, each 48x64 (3x4 MFMA 16x16x32 frags).
// Operands read straight from L2 (A=460KB, Xt_b=240KB cache-resident), no LDS.
__global__ __launch_bounds__(256, 2)
void k_gemm(const unsigned short* __restrict__ A, const unsigned short* __restrict__ Xt,
            const float* __restrict__ x, float* __restrict__ out0, float* __restrict__ out1) {
    int b = blockIdx.y;
    int t0 = blockIdx.x * 48;
    int tid = threadIdx.x;
    int wave = tid >> 6, lane = tid & 63;
    int lane15 = lane & 15, quad = lane >> 4;
    int cbase = wave * 64;

    const unsigned short* ap[3];
    #pragma unroll
    for (int i = 0; i < 3; ++i)
        ap[i] = A + (size_t)(t0 + i * 16 + lane15) * TLEN + quad * 8;
    const unsigned short* bp[4];
    #pragma unroll
    for (int j = 0; j < 4; ++j)
        bp[j] = Xt + ((size_t)b * NC + cbase + j * 16 + lane15) * TLEN + quad * 8;

    f32x4 acc[3][4] = {};
    for (int k0 = 0; k0 < TLEN; k0 += 32) {
        bf16x8 af[3], bf[4];
        #pragma unroll
        for (int i = 0; i < 3; ++i) af[i] = *(const bf16x8*)(ap[i] + k0);
        #pragma unroll
        for (int j = 0; j < 4; ++j) bf[j] = *(const bf16x8*)(bp[j] + k0);
        #pragma unroll
        for (int i = 0; i < 3; ++i)
            #pragma unroll
            for (int j = 0; j < 4; ++j)
                acc[i][j] = __builtin_amdgcn_mfma_f32_16x16x32_bf16(af[i], bf[j], acc[i][j], 0, 0, 0);
    }

    #pragma unroll
    for (int i = 0; i < 3; ++i) {
        #pragma unroll
        for (int r = 0; r < 4; ++r) {
            int t = t0 + i * 16 + quad * 4 + r;
            size_t rowbase = ((size_t)b * TLEN + t) * NC;
            #pragma unroll
            for (int j = 0; j < 4; ++j) {
                int c = cbase + j * 16 + lane15;
                float v = acc[i][j][r];
                out1[rowbase + c] = v;
                out0[rowbase + c] = x[rowbase + c] - v;
            }
        }
    }
}

extern "C" void kernel_launch(void* const* d_in, const int* in_sizes, int n_in,
                              void* d_out, int out_size, void* d_ws, size_t ws_size,
                              hipStream_t stream) {
    const float* x = (const float*)d_in[0];
    float* out0 = (float*)d_out;                       // seasonal + resid = x - trend
    float* out1 = (float*)d_out + (size_t)NB * TLEN * NC;  // trend

    char* ws = (char*)d_ws;
    size_t oXt = 0;                                // 128*256*480*2 = 31,457,280 B
    size_t oMs = 31457280;                         // 34*32*4 = 4352
    size_t oW3 = oMs + 4352;                       // 128
    size_t oLp = oW3 + 128;                        // 921600
    size_t oMt = oLp + 921600;
    size_t oG  = oMt + 921600;
    size_t oS  = oG + 921600;
    size_t oU  = oS + 921600;
    size_t oV  = oU + 921600;
    size_t oA  = oV + 921600;                      // bf16 460800

    unsigned short* Xt = (unsigned short*)(ws + oXt);
    float* Ms  = (float*)(ws + oMs);
    float* w3  = (float*)(ws + oW3);
    float* Mlp = (float*)(ws + oLp);
    float* Mt  = (float*)(ws + oMt);
    float* G   = (float*)(ws + oG);
    float* S   = (float*)(ws + oS);
    float* U   = (float*)(ws + oU);
    float* V   = (float*)(ws + oV);
    unsigned short* Abf = (unsigned short*)(ws + oA);

    // zero M_seas/w3/M_lp/M_trend region (rows only write their LOESS windows)
    int nzero = (4352 + 128 + 921600 * 2) / 4;
    k_zero<<<(nzero + 255) / 256, 256, 0, stream>>>((float*)(ws + oMs), nzero);
    k_loess<<<1, 1024, 0, stream>>>(Ms, w3, Mlp, Mt);
    k_G<<<900, 256, 0, stream>>>(Ms, w3, G);
    k_S<<<900, 256, 0, stream>>>(Ms, Mlp, G, S);
    k_VU<<<900, 256, 0, stream>>>(Mt, S, U, V);
    k_A<<<dim3(30, 30), dim3(16, 16), 0, stream>>>(U, V, Abf);
    k_tr<<<dim3(8, 15, NB), 256, 0, stream>>>(x, Xt);
    k_gemm<<<dim3(10, NB), 256, 0, stream>>>(Abf, Xt, x, out0, out1);
}

// Round 2
// 289.454 us; speedup vs baseline: 1.0931x; 1.0931x over previous
//
#include <hip/hip_runtime.h>
#include <hip/hip_bf16.h>
#include <stdint.h>

#define TLEN 480
#define NB 128
#define NC 256

typedef short bf16x8 __attribute__((ext_vector_type(8)));
typedef float f32x4 __attribute__((ext_vector_type(4)));
typedef unsigned short u16;

__device__ inline u16 f2bf(float f) {
    union { float f; uint32_t u; } v; v.f = f;
    uint32_t u = v.u;
    return (u16)((u + 0x7fffu + ((u >> 16) & 1u)) >> 16);
}

// degree-1 LOESS weights, compact: fills w[0..q-1] for columns [left, left+q-1], returns left.
__device__ int loess_w(int t, int n, int q, float* out) {
    int left = t - (q - 1) / 2;
    if (left < 0) left = 0;
    if (left > n - q) left = n - q;
    int right = left + q - 1;
    int h = (t - left) > (right - t) ? (t - left) : (right - t);
    double w[29];
    double wsum = 0.0;
    for (int i = 0; i < q; ++i) {
        double dist = fabs((double)(left + i - t)) / (double)h;
        double u = 1.0 - dist * dist * dist;
        if (u < 0.0) u = 0.0;
        double wv = u * u * u;
        w[i] = wv; wsum += wv;
    }
    for (int i = 0; i < q; ++i) w[i] /= wsum;
    double xbar = 0.0;
    for (int i = 0; i < q; ++i) xbar += w[i] * (double)(left + i);
    double var = 0.0;
    for (int i = 0; i < q; ++i) { double d = (double)(left + i) - xbar; var += w[i] * d * d; }
    if (var > 1e-12) {
        double tb = (double)t - xbar;
        for (int i = 0; i < q; ++i) {
            double d = (double)(left + i) - xbar;
            out[i] = (float)(w[i] * (1.0 + tb * d / var));
        }
    } else {
        for (int i = 0; i < q; ++i) out[i] = (float)w[i];
    }
    return left;
}

// Ms dense (34x32), MlpC (480x17 compact), MtC (480x29 compact), w3 (31-tap MA15*MA15*MA3)
__global__ void k_loess(float* Ms, float* w3, float* MlpC, float* MtC) {
    int gid = blockIdx.x * 256 + threadIdx.x;
    if (gid < 34) {
        float wl[7];
        int left = loess_w(gid - 1, 32, 7, wl);
        float* row = Ms + gid * 32;
        #pragma unroll
        for (int i = 0; i < 32; ++i) row[i] = 0.0f;
        for (int i = 0; i < 7; ++i) row[left + i] = wl[i];
    } else if (gid < 514) {
        int t = gid - 34;
        float wl[17];
        loess_w(t, TLEN, 17, wl);
        for (int i = 0; i < 17; ++i) MlpC[t * 17 + i] = wl[i];
    } else if (gid < 994) {
        int t = gid - 514;
        float wl[29];
        loess_w(t, TLEN, 29, wl);
        for (int i = 0; i < 29; ++i) MtC[t * 29 + i] = wl[i];
    } else if (gid == 994) {
        for (int d = 0; d <= 30; ++d) {
            int cnt = 0;
            for (int c = 0; c < 3; ++c)
                for (int a = 0; a < 15; ++a) {
                    int b = d - a - c;
                    if (b >= 0 && b < 15) cnt++;
                }
            w3[d] = (float)((double)cnt / 675.0);
        }
    }
}

// S[t][u] = Ecenter[t][u] - sum_{k<17} MlpC[t][k] * G[slp(t)+k][u],
// G[i][u] = sum_s Ms[s][u/15]*w3[s*15 + u%15 - i]  (<=3 live s terms)
__global__ void k_S(const float* __restrict__ Ms, const float* __restrict__ w3,
                    const float* __restrict__ MlpC, float* __restrict__ S) {
    int id = blockIdx.x * 256 + threadIdx.x;
    if (id >= TLEN * TLEN) return;
    int t = id / TLEN, u = id - t * TLEN;
    int nu = u / 15, ju = u - nu * 15;
    int slp = t - 8;
    if (slp < 0) slp = 0;
    if (slp > TLEN - 17) slp = TLEN - 17;
    float acc = 0.0f;
    for (int k = 0; k < 17; ++k) {
        int i = slp + k;
        int s_lo = (i - ju + 14) / 15;   // i-ju >= -14, so trunc == ceil
        float g = 0.0f;
        #pragma unroll
        for (int ds = 0; ds < 3; ++ds) {
            int s = s_lo + ds;
            int d = s * 15 + ju - i;
            if (s >= 0 && s < 34 && d >= 0 && d <= 30)
                g += Ms[s * 32 + nu] * w3[d];
        }
        acc += MlpC[t * 17 + k] * g;
    }
    float val = -acc;
    if (t % 15 == ju) val += Ms[(1 + t / 15) * 32 + nu];
    S[id] = val;
}

// V = Mt @ S (banded 29), U = Mt - V (Mt from compact)
__global__ void k_VU(const float* __restrict__ MtC, const float* __restrict__ S,
                     float* __restrict__ U, float* __restrict__ V) {
    int id = blockIdx.x * 256 + threadIdx.x;
    if (id >= TLEN * TLEN) return;
    int t = id / TLEN, u = id - t * TLEN;
    int st = t - 14;
    if (st < 0) st = 0;
    if (st > TLEN - 29) st = TLEN - 29;
    float acc = 0.0f;
    for (int k = 0; k < 29; ++k)
        acc += MtC[t * 29 + k] * S[(size_t)(st + k) * TLEN + u];
    float mt = (u >= st && u < st + 29) ? MtC[t * 29 + (u - st)] : 0.0f;
    V[id] = acc;
    U[id] = mt - acc;
}

// A = U + V@U, output bf16; 16x16 LDS-tiled fp32 matmul (480^3, tiny)
__global__ void k_A(const float* __restrict__ U, const float* __restrict__ V,
                    u16* __restrict__ Abf) {
    __shared__ float Vs[16][17];
    __shared__ float Us[16][17];
    int tx = threadIdx.x, ty = threadIdx.y;
    int u = blockIdx.x * 16 + tx;
    int t = blockIdx.y * 16 + ty;
    float acc = 0.0f;
    for (int kt = 0; kt < 30; ++kt) {
        Vs[ty][tx] = V[(size_t)t * TLEN + kt * 16 + tx];
        Us[ty][tx] = U[(size_t)(kt * 16 + ty) * TLEN + u];
        __syncthreads();
        #pragma unroll
        for (int e = 0; e < 16; ++e) acc += Vs[ty][e] * Us[e][tx];
        __syncthreads();
    }
    Abf[(size_t)t * TLEN + u] = f2bf(U[(size_t)t * TLEN + u] + acc);
}

// x [128][480][256] fp32 -> Xt [128][256][480] bf16 (tile transpose via LDS)
__global__ void k_tr(const float* __restrict__ x, u16* __restrict__ Xt) {
    __shared__ u16 Tt[32 * 36];
    int b = blockIdx.z, s0 = blockIdx.y * 32, c0 = blockIdx.x * 32;
    int i = threadIdx.x;
    int r = i >> 3, cg = i & 7;
    float4 v = *(const float4*)(x + (((size_t)b * TLEN + s0 + r) * NC + c0 + cg * 4));
    Tt[(cg * 4 + 0) * 36 + r] = f2bf(v.x);
    Tt[(cg * 4 + 1) * 36 + r] = f2bf(v.y);
    Tt[(cg * 4 + 2) * 36 + r] = f2bf(v.z);
    Tt[(cg * 4 + 3) * 36 + r] = f2bf(v.w);
    __syncthreads();
    int cl = i >> 3, ch = i & 7;
    ushort4 o = *(const ushort4*)&Tt[cl * 36 + ch * 4];
    *(ushort4*)(Xt + (((size_t)b * NC + c0 + cl) * TLEN + s0 + ch * 4)) = o;
}

// trend = A @ X_b; out1 = trend, out0 = x - trend.
// Operand-swapped MFMA: D[m=c][n=t] so each lane holds 4 consecutive c -> float4 epilogue.
// Grid (128 batches, 10 t-tiles): batch on x => all 10 blocks of batch b land on XCD b%8
// (round-robin heuristic) so Xt_b (240 KB) is fetched into one XCD's L2 only.
__global__ __launch_bounds__(256, 4)
void k_gemm(const u16* __restrict__ A, const u16* __restrict__ Xt,
            const float* __restrict__ x, float* __restrict__ out0, float* __restrict__ out1) {
    int b = blockIdx.x;
    int t0 = blockIdx.y * 48;
    int tid = threadIdx.x;
    int wave = tid >> 6, lane = tid & 63;
    int lane15 = lane & 15, quad = lane >> 4;
    int cw = wave * 64;

    // A-operand (m = c): Xt rows
    const u16* ap[4];
    #pragma unroll
    for (int i = 0; i < 4; ++i)
        ap[i] = Xt + ((size_t)b * NC + cw + i * 16 + lane15) * TLEN + quad * 8;
    // B-operand (n = t): A-matrix rows
    const u16* bp[3];
    #pragma unroll
    for (int j = 0; j < 3; ++j)
        bp[j] = A + (size_t)(t0 + j * 16 + lane15) * TLEN + quad * 8;

    f32x4 acc[4][3] = {};
    for (int k0 = 0; k0 < TLEN; k0 += 32) {
        bf16x8 af[4], bfr[3];
        #pragma unroll
        for (int i = 0; i < 4; ++i) af[i] = *(const bf16x8*)(ap[i] + k0);
        #pragma unroll
        for (int j = 0; j < 3; ++j) bfr[j] = *(const bf16x8*)(bp[j] + k0);
        #pragma unroll
        for (int i = 0; i < 4; ++i)
            #pragma unroll
            for (int j = 0; j < 3; ++j)
                acc[i][j] = __builtin_amdgcn_mfma_f32_16x16x32_bf16(af[i], bfr[j], acc[i][j], 0, 0, 0);
    }

    // D[m=c][n=t]: col(lane15) = t-offset, row(quad*4+r) = c-offset -> float4 in c
    #pragma unroll
    for (int i = 0; i < 4; ++i) {
        #pragma unroll
        for (int j = 0; j < 3; ++j) {
            int t = t0 + j * 16 + lane15;
            int c = cw + i * 16 + quad * 4;
            size_t base = ((size_t)b * TLEN + t) * NC + c;
            float4 xv = *(const float4*)(x + base);
            float4 tv = make_float4(acc[i][j][0], acc[i][j][1], acc[i][j][2], acc[i][j][3]);
            *(float4*)(out1 + base) = tv;
            *(float4*)(out0 + base) = make_float4(xv.x - tv.x, xv.y - tv.y, xv.z - tv.z, xv.w - tv.w);
        }
    }
}

extern "C" void kernel_launch(void* const* d_in, const int* in_sizes, int n_in,
                              void* d_out, int out_size, void* d_ws, size_t ws_size,
                              hipStream_t stream) {
    const float* x = (const float*)d_in[0];
    float* out0 = (float*)d_out;                           // seasonal + resid = x - trend
    float* out1 = (float*)d_out + (size_t)NB * TLEN * NC;  // trend

    char* ws = (char*)d_ws;
    size_t oXt  = 0;                       // 128*256*480*2 = 31,457,280
    size_t oMs  = 31457280;                // 34*32*4 = 4352
    size_t oW3  = oMs + 4352;              // 128
    size_t oLpC = oW3 + 128;               // 480*17*4 = 32640
    size_t oMtC = oLpC + 32640;            // 480*29*4 = 55680
    size_t oS   = oMtC + 55680;            // 921600
    size_t oU   = oS + 921600;
    size_t oV   = oU + 921600;
    size_t oA   = oV + 921600;             // bf16 460800

    u16*   Xt   = (u16*)(ws + oXt);
    float* Ms   = (float*)(ws + oMs);
    float* w3   = (float*)(ws + oW3);
    float* MlpC = (float*)(ws + oLpC);
    float* MtC  = (float*)(ws + oMtC);
    float* S    = (float*)(ws + oS);
    float* U    = (float*)(ws + oU);
    float* V    = (float*)(ws + oV);
    u16*   Abf  = (u16*)(ws + oA);

    k_loess<<<4, 256, 0, stream>>>(Ms, w3, MlpC, MtC);
    k_S<<<900, 256, 0, stream>>>(Ms, w3, MlpC, S);
    k_VU<<<900, 256, 0, stream>>>(MtC, S, U, V);
    k_A<<<dim3(30, 30), dim3(16, 16), 0, stream>>>(U, V, Abf);
    k_tr<<<dim3(8, 15, NB), 256, 0, stream>>>(x, Xt);
    k_gemm<<<dim3(NB, 10), 256, 0, stream>>>(Abf, Xt, x, out0, out1);
}

// Round 4
// 287.778 us; speedup vs baseline: 1.0995x; 1.0058x over previous
//
#include <hip/hip_runtime.h>
#include <hip/hip_bf16.h>
#include <stdint.h>

#define TLEN 480
#define NB 128
#define NC 256

typedef short bf16x8 __attribute__((ext_vector_type(8)));
typedef float f32x4 __attribute__((ext_vector_type(4)));
typedef unsigned short u16;
typedef unsigned int u32;

__device__ inline u16 f2bf(float f) {   // RNE, used for the A operator (built once)
    union { float f; uint32_t u; } v; v.f = f;
    uint32_t u = v.u;
    return (u16)((u + 0x7fffu + ((u >> 16) & 1u)) >> 16);
}

// pack two fp32 -> (bf16(hi)<<16)|bf16(lo) by truncation: one v_perm_b32
__device__ inline u32 pack2bf(float lo, float hi) {
    return __builtin_amdgcn_perm(__float_as_uint(hi), __float_as_uint(lo), 0x07060302u);
}

// degree-1 LOESS weights, compact: fills w[0..q-1] for columns [left, left+q-1], returns left.
__device__ int loess_w(int t, int n, int q, float* out) {
    int left = t - (q - 1) / 2;
    if (left < 0) left = 0;
    if (left > n - q) left = n - q;
    int right = left + q - 1;
    int h = (t - left) > (right - t) ? (t - left) : (right - t);
    double w[29];
    double wsum = 0.0;
    for (int i = 0; i < q; ++i) {
        double dist = fabs((double)(left + i - t)) / (double)h;
        double u = 1.0 - dist * dist * dist;
        if (u < 0.0) u = 0.0;
        double wv = u * u * u;
        w[i] = wv; wsum += wv;
    }
    for (int i = 0; i < q; ++i) w[i] /= wsum;
    double xbar = 0.0;
    for (int i = 0; i < q; ++i) xbar += w[i] * (double)(left + i);
    double var = 0.0;
    for (int i = 0; i < q; ++i) { double d = (double)(left + i) - xbar; var += w[i] * d * d; }
    if (var > 1e-12) {
        double tb = (double)t - xbar;
        for (int i = 0; i < q; ++i) {
            double d = (double)(left + i) - xbar;
            out[i] = (float)(w[i] * (1.0 + tb * d / var));
        }
    } else {
        for (int i = 0; i < q; ++i) out[i] = (float)w[i];
    }
    return left;
}

// Ms dense (34x32), MlpC (480x17 compact), MtC (480x29 compact), w3 (31-tap MA15*MA15*MA3)
__global__ void k_loess(float* Ms, float* w3, float* MlpC, float* MtC) {
    int gid = blockIdx.x * 256 + threadIdx.x;
    if (gid < 34) {
        float wl[7];
        int left = loess_w(gid - 1, 32, 7, wl);
        float* row = Ms + gid * 32;
        #pragma unroll
        for (int i = 0; i < 32; ++i) row[i] = 0.0f;
        for (int i = 0; i < 7; ++i) row[left + i] = wl[i];
    } else if (gid < 514) {
        int t = gid - 34;
        float wl[17];
        loess_w(t, TLEN, 17, wl);
        for (int i = 0; i < 17; ++i) MlpC[t * 17 + i] = wl[i];
    } else if (gid < 994) {
        int t = gid - 514;
        float wl[29];
        loess_w(t, TLEN, 29, wl);
        for (int i = 0; i < 29; ++i) MtC[t * 29 + i] = wl[i];
    } else if (gid == 994) {
        for (int d = 0; d <= 30; ++d) {
            int cnt = 0;
            for (int c = 0; c < 3; ++c)
                for (int a = 0; a < 15; ++a) {
                    int b = d - a - c;
                    if (b >= 0 && b < 15) cnt++;
                }
            w3[d] = (float)((double)cnt / 675.0);
        }
    }
}

// S[t][u] = Ecenter[t][u] - sum_{k<17} MlpC[t][k] * G[slp(t)+k][u]
__global__ void k_S(const float* __restrict__ Ms, const float* __restrict__ w3,
                    const float* __restrict__ MlpC, float* __restrict__ S) {
    int id = blockIdx.x * 256 + threadIdx.x;
    if (id >= TLEN * TLEN) return;
    int t = id / TLEN, u = id - t * TLEN;
    int nu = u / 15, ju = u - nu * 15;
    int slp = t - 8;
    if (slp < 0) slp = 0;
    if (slp > TLEN - 17) slp = TLEN - 17;
    float acc = 0.0f;
    for (int k = 0; k < 17; ++k) {
        int i = slp + k;
        int s_lo = (i - ju + 14) / 15;
        float g = 0.0f;
        #pragma unroll
        for (int ds = 0; ds < 3; ++ds) {
            int s = s_lo + ds;
            int d = s * 15 + ju - i;
            if (s >= 0 && s < 34 && d >= 0 && d <= 30)
                g += Ms[s * 32 + nu] * w3[d];
        }
        acc += MlpC[t * 17 + k] * g;
    }
    float val = -acc;
    if (t % 15 == ju) val += Ms[(1 + t / 15) * 32 + nu];
    S[id] = val;
}

// V = Mt @ S (banded 29), U = Mt - V (Mt from compact)
__global__ void k_VU(const float* __restrict__ MtC, const float* __restrict__ S,
                     float* __restrict__ U, float* __restrict__ V) {
    int id = blockIdx.x * 256 + threadIdx.x;
    if (id >= TLEN * TLEN) return;
    int t = id / TLEN, u = id - t * TLEN;
    int st = t - 14;
    if (st < 0) st = 0;
    if (st > TLEN - 29) st = TLEN - 29;
    float acc = 0.0f;
    for (int k = 0; k < 29; ++k)
        acc += MtC[t * 29 + k] * S[(size_t)(st + k) * TLEN + u];
    float mt = (u >= st && u < st + 29) ? MtC[t * 29 + (u - st)] : 0.0f;
    V[id] = acc;
    U[id] = mt - acc;
}

// A = U + V@U, output bf16 (RNE); 16x16 LDS-tiled fp32 matmul (480^3, tiny)
__global__ void k_A(const float* __restrict__ U, const float* __restrict__ V,
                    u16* __restrict__ Abf) {
    __shared__ float Vs[16][17];
    __shared__ float Us[16][17];
    int tx = threadIdx.x, ty = threadIdx.y;
    int u = blockIdx.x * 16 + tx;
    int t = blockIdx.y * 16 + ty;
    float acc = 0.0f;
    for (int kt = 0; kt < 30; ++kt) {
        Vs[ty][tx] = V[(size_t)t * TLEN + kt * 16 + tx];
        Us[ty][tx] = U[(size_t)(kt * 16 + ty) * TLEN + u];
        __syncthreads();
        #pragma unroll
        for (int e = 0; e < 16; ++e) acc += Vs[ty][e] * Us[e][tx];
        __syncthreads();
    }
    Abf[(size_t)t * TLEN + u] = f2bf(U[(size_t)t * TLEN + u] + acc);
}

// Fused transpose+GEMM: trend = A @ x_b^T per batch; out1 = trend, out0 = x - trend.
// Per k-step, stage x[b, k0:k0+32, 0:256] -> LDS bf16 in [c][k] layout (stride 40 u16),
// with k-group XOR swizzle (group g of column c stored at g ^ ((c>>2)&3)) so:
//   - staging writes: ds_write_b64 (4 k's per c), ~data-bound on banks
//   - frag reads: ds_read_b128 at 16B-aligned addrs, ~2-way max
// MFMA D[m=c][n=t] -> f32x4 epilogue in c. Batch on blockIdx.x => all 10 t-blocks of
// batch b on XCD b%8, sweeping k in lockstep => x_b fetched ~once per XCD.
__global__ __launch_bounds__(256, 4)
void k_gemm(const u16* __restrict__ A, const float* __restrict__ x,
            float* __restrict__ out0, float* __restrict__ out1) {
    __shared__ u16 Xs[NC * 40];
    int b = blockIdx.x;
    int t0 = blockIdx.y * 48;
    int tid = threadIdx.x;
    int wave = tid >> 6, lane = tid & 63;
    int lane15 = lane & 15, quad = lane >> 4;
    int cw = wave * 64;

    // B-operand (n = t): rows of the A operator (bf16, L2-resident 460 KB)
    const u16* bp[3];
    #pragma unroll
    for (int j = 0; j < 3; ++j)
        bp[j] = A + (size_t)(t0 + j * 16 + lane15) * TLEN + quad * 8;

    // staging role: thread handles k-quad kkq (4 rows) x two c-quads
    int kkq = tid >> 5;          // 0..7
    int wq  = tid & 31;          // c-quad index within 128-c half
    int kq_sw = kkq ^ ((wq & 3) << 1);   // swizzled k-halfgroup position

    const float* xbase = x + (size_t)b * TLEN * NC;

    f32x4 acc[4][3] = {};
    for (int s = 0; s < 15; ++s) {
        int k0 = s * 32;
        if (s) __syncthreads();   // previous step's frag reads done
        #pragma unroll
        for (int it = 0; it < 2; ++it) {
            int c0 = wq * 4 + it * 128;
            const float* xp = xbase + (size_t)(k0 + kkq * 4) * NC + c0;
            float4 r0 = *(const float4*)(xp);
            float4 r1 = *(const float4*)(xp + NC);
            float4 r2 = *(const float4*)(xp + 2 * NC);
            float4 r3 = *(const float4*)(xp + 3 * NC);
            u32* base32 = (u32*)Xs;
            int o0 = c0 * 20 + kq_sw * 2;    // u32 offset = ((c)*40 + kq_sw*4)/2
            uint2 w;
            w.x = pack2bf(r0.x, r1.x); w.y = pack2bf(r2.x, r3.x);
            *(uint2*)(base32 + o0) = w;
            w.x = pack2bf(r0.y, r1.y); w.y = pack2bf(r2.y, r3.y);
            *(uint2*)(base32 + o0 + 20) = w;
            w.x = pack2bf(r0.z, r1.z); w.y = pack2bf(r2.z, r3.z);
            *(uint2*)(base32 + o0 + 40) = w;
            w.x = pack2bf(r0.w, r1.w); w.y = pack2bf(r2.w, r3.w);
            *(uint2*)(base32 + o0 + 60) = w;
        }
        __syncthreads();

        bf16x8 af[4], bfr[3];
        #pragma unroll
        for (int i = 0; i < 4; ++i) {
            int c = cw + i * 16 + lane15;
            int qp = quad ^ ((c >> 2) & 3);
            af[i] = *(const bf16x8*)&Xs[c * 40 + qp * 8];
        }
        #pragma unroll
        for (int j = 0; j < 3; ++j) bfr[j] = *(const bf16x8*)(bp[j] + k0);
        #pragma unroll
        for (int i = 0; i < 4; ++i)
            #pragma unroll
            for (int j = 0; j < 3; ++j)
                acc[i][j] = __builtin_amdgcn_mfma_f32_16x16x32_bf16(af[i], bfr[j], acc[i][j], 0, 0, 0);
    }

    // D[m=c][n=t]: col(lane15) = t-offset, row(quad*4+r) = c-offset -> f32x4 in c.
    // Non-temporal stores: don't let the 126 MB output stream evict shared x/A in L2.
    #pragma unroll
    for (int i = 0; i < 4; ++i) {
        #pragma unroll
        for (int j = 0; j < 3; ++j) {
            int t = t0 + j * 16 + lane15;
            int c = cw + i * 16 + quad * 4;
            size_t base = ((size_t)b * TLEN + t) * NC + c;
            f32x4 xv = *(const f32x4*)(x + base);
            f32x4 tv = acc[i][j];
            __builtin_nontemporal_store(tv, (f32x4*)(out1 + base));
            f32x4 sv = xv - tv;
            __builtin_nontemporal_store(sv, (f32x4*)(out0 + base));
        }
    }
}

extern "C" void kernel_launch(void* const* d_in, const int* in_sizes, int n_in,
                              void* d_out, int out_size, void* d_ws, size_t ws_size,
                              hipStream_t stream) {
    const float* x = (const float*)d_in[0];
    float* out0 = (float*)d_out;                           // seasonal + resid = x - trend
    float* out1 = (float*)d_out + (size_t)NB * TLEN * NC;  // trend

    char* ws = (char*)d_ws;
    size_t oMs  = 0;                       // 34*32*4 = 4352
    size_t oW3  = oMs + 4352;              // 128
    size_t oLpC = oW3 + 128;               // 480*17*4 = 32640
    size_t oMtC = oLpC + 32640;            // 480*29*4 = 55680
    size_t oS   = oMtC + 55680;            // 921600
    size_t oU   = oS + 921600;
    size_t oV   = oU + 921600;
    size_t oA   = oV + 921600;             // bf16 460800

    float* Ms   = (float*)(ws + oMs);
    float* w3   = (float*)(ws + oW3);
    float* MlpC = (float*)(ws + oLpC);
    float* MtC  = (float*)(ws + oMtC);
    float* S    = (float*)(ws + oS);
    float* U    = (float*)(ws + oU);
    float* V    = (float*)(ws + oV);
    u16*   Abf  = (u16*)(ws + oA);

    k_loess<<<4, 256, 0, stream>>>(Ms, w3, MlpC, MtC);
    k_S<<<900, 256, 0, stream>>>(Ms, w3, MlpC, S);
    k_VU<<<900, 256, 0, stream>>>(MtC, S, U, V);
    k_A<<<dim3(30, 30), dim3(16, 16), 0, stream>>>(U, V, Abf);
    k_gemm<<<dim3(NB, 10), 256, 0, stream>>>(Abf, x, out0, out1);
}